// Round 1
// baseline (322.409 us; speedup 1.0000x reference)
//
#include <hip/hip_runtime.h>
#include <math.h>

#define NQ     12
#define NSTATE 4096
#define NDEPTH 4
#define HID    64
#define NPAR   (NDEPTH*NQ*3)   // 144
#define NGATE  (NDEPTH*NQ)     // 48
#define TPB    256
#define NPASS  (NDEPTH*3)      // 12 passes, 4 gates each

// ---------------- compile-time GF(2) machinery for lazy CNOT folding ----------------
// CNOT(c,t) maps basis i -> i ^ (bit_{c'}(i)<<t'), a GF(2)-linear map F (c'=11-c, t'=11-t).
// Reference applies, per layer: 12 single-qubit gates, then the CNOT ring.
// We never permute the state. storage[p] = psi[M_l p] where M_l = (F11*...*F0)^l.
// Gate on qubit q (basis bit b=11-q) in layer l: pairs p <-> p^v, v = column b of M_l^{-1},
// role(p) = parity(row_b(M_l) & p).  Note row_j(M) . col_i(M^{-1}) = delta_ij, so with
// register slots indexed by coefficients over {v_i}, role_j(slot z) = parity(r_j&rep) ^ z_j.

struct PassT { unsigned v[4]; unsigned r[4]; unsigned w[8]; };
struct Tables { PassT pass[NPASS]; unsigned rfin[NQ]; };
struct GF12 { unsigned row[12]; };

constexpr GF12 gf_id() { GF12 m{}; for (int i=0;i<12;i++) m.row[i]=1u<<i; return m; }
constexpr GF12 gf_mul(const GF12&A, const GF12&B){
  GF12 r{};
  for (int i=0;i<12;i++){ unsigned acc=0;
    for (int k=0;k<12;k++) if ((A.row[i]>>k)&1u) acc ^= B.row[k];
    r.row[i]=acc; }
  return r;
}
constexpr GF12 gf_cnot(int q){ GF12 m=gf_id(); int c=11-q, t=11-((q+1)%12); m.row[t]^=(1u<<c); return m; }

constexpr Tables make_tables(){
  Tables T{};
  GF12 D = gf_id();            // ring^{-1} as storage-map step: F11*...*F0
  for (int q=0;q<12;q++) D = gf_mul(gf_cnot(q), D);
  GF12 C = gf_id();            // its inverse: F0*...*F11
  for (int q=11;q>=0;q--) C = gf_mul(gf_cnot(q), C);
  GF12 M = gf_id(), Minv = gf_id();
  for (int l=0;l<NDEPTH;l++){
    for (int q=0;q<12;q++){
      int b = 11-q;
      unsigned v=0;
      for (int j=0;j<12;j++) v |= ((Minv.row[j]>>b)&1u)<<j;  // column b of M^{-1}
      int pass = l*3 + q/4;
      T.pass[pass].v[q&3] = v;
      T.pass[pass].r[q&3] = M.row[b];
    }
    // per-pass complement basis w[0..7] (coset representatives rep = xor of tid-selected w's).
    // w[0..3] are forced to have low-4-bits = e_i so the 64 lanes cover all 16 LDS
    // bank-pair residues -> minimal 4 dwords/bank for wave64 b64 access (conflict-free).
    for (int pg=0;pg<3;pg++){
      int pass = l*3+pg;
      unsigned red[12]={}; int hb[12]={}; int nred=0;
      for (int i=0;i<4;i++){
        unsigned y = T.pass[pass].v[i];
        for (int t=0;t<nred;t++) if ((y>>hb[t])&1u) y ^= red[t];
        int h=11; while (h>0 && !((y>>h)&1u)) h--;
        red[nred]=y; hb[nred]=h; nred++;
      }
      for (int i=0;i<8;i++){
        unsigned chosen=0;
        for (unsigned cand=0; cand<4096 && !chosen; cand++){
          if (i<4 && cand>=256) break;
          unsigned x = (i<4) ? ((1u<<i) | (cand<<4)) : cand;
          if (x==0) continue;
          unsigned y=x;
          for (int t=0;t<nred;t++) if ((y>>hb[t])&1u) y ^= red[t];
          if (y){ chosen=x; int h=11; while (h>0 && !((y>>h)&1u)) h--;
                  red[nred]=y; hb[nred]=h; nred++; }
        }
        T.pass[pass].w[i]=chosen;
      }
    }
    M = gf_mul(D, M); Minv = gf_mul(C, Minv);
  }
  for (int q=0;q<12;q++) T.rfin[q] = M.row[11-q];   // final measurement rows
  return T;
}

constexpr bool verify_tables(const Tables& T){
  for (int pass=0; pass<NPASS; pass++){
    // r_j . v_i = delta_ij  (the role identity the kernel relies on)
    for (int j=0;j<4;j++)
      for (int i=0;i<4;i++){
        unsigned x = T.pass[pass].r[j] & T.pass[pass].v[i]; int p=0;
        for (int b=0;b<12;b++) p ^= (int)((x>>b)&1u);
        if (p != ((i==j)?1:0)) return false;
      }
    // {v0..3, w0..7} must span GF(2)^12 (cosets disjoint + covering)
    unsigned red[12]={}; int hb[12]={}; int n=0;
    for (int i=0;i<12;i++){
      unsigned y = (i<4) ? T.pass[pass].v[i] : T.pass[pass].w[i-4];
      for (int t=0;t<n;t++) if ((y>>hb[t])&1u) y^=red[t];
      if (!y) return false;
      int h=11; while (h>0 && !((y>>h)&1u)) h--;
      red[n]=y; hb[n]=h; n++;
    }
    for (int i=0;i<4;i++) if ((T.pass[pass].w[i] & 15u) != (1u<<i)) return false;
  }
  return true;
}

constexpr Tables hT = make_tables();
static_assert(verify_tables(hT), "GF(2) table self-check failed");
__constant__ Tables cT = hT;

// ---------------- kernel: one workgroup per batch element ----------------
__global__ void __launch_bounds__(TPB)
qgen(const float* __restrict__ noise,
     const float* __restrict__ W1, const float* __restrict__ b1,
     const float* __restrict__ W2, const float* __restrict__ b2,
     const float* __restrict__ W3, const float* __restrict__ b3,
     const float* __restrict__ W4, const float* __restrict__ b4,
     float* __restrict__ out)
{
  __shared__ float2 s[NSTATE];          // 32 KB state
  __shared__ float  h_sh[HID];
  __shared__ float  par_sh[NPAR];
  __shared__ float4 ug_sh[NGATE];       // per gate: (u0r,u0i,u1r,u1i); U=[[u0,u1],[-conj(u1),conj(u0)]]
  __shared__ float  red_sh[TPB/64][NQ];
  __shared__ float  meas_sh[NQ];
  __shared__ float  noise_sh[NQ];

  const int tid  = threadIdx.x;
  const int bidx = blockIdx.x;

  // init |0...0>
  #pragma unroll
  for (int k=0;k<NSTATE/TPB;k++) s[tid + TPB*k] = make_float2(0.f, 0.f);
  if (tid==0) s[0] = make_float2(1.f, 0.f);
  if (tid<NQ) noise_sh[tid] = noise[bidx*NQ + tid];
  __syncthreads();

  // MLP prologue: h = tanh(noise@W1+b1)
  if (tid < HID){
    float a = b1[tid];
    #pragma unroll
    for (int k=0;k<NQ;k++) a = fmaf(noise_sh[k], W1[k*HID+tid], a);
    h_sh[tid] = tanhf(a);
  }
  __syncthreads();
  // params = h@W2+b2
  if (tid < NPAR){
    float a = b2[tid];
    #pragma unroll 16
    for (int j=0;j<HID;j++) a = fmaf(h_sh[j], W2[j*NPAR+tid], a);
    par_sh[tid] = a;
  }
  __syncthreads();
  // U3 gate matrices: U = RZ(c)RY(b)RX(a); SU(2): store u0=U00, u1=U01
  if (tid < NGATE){
    float aa = par_sh[3*tid+0]*0.5f;
    float bb = par_sh[3*tid+1]*0.5f;
    float c  = par_sh[3*tid+2]*0.5f;
    float sa,ca,sb,cb,sc,cc;
    __sincosf(aa,&sa,&ca); __sincosf(bb,&sb,&cb); __sincosf(c,&sc,&cc);
    float A=cb*ca, B=sb*sa, Cc=sb*ca, Dd=cb*sa;
    ug_sh[tid] = make_float4(fmaf(cc,A,  sc*B),  fmaf(cc,B, -sc*A),
                             fmaf(-cc,Cc,-sc*Dd), fmaf(sc,Cc,-cc*Dd));
  }
  __syncthreads();

  // 12 radix-16 passes: 4 gates per LDS round-trip
  for (int pass=0; pass<NPASS; ++pass){
    const PassT P = cT.pass[pass];

    unsigned rep = 0u;
    #pragma unroll
    for (int i=0;i<8;i++) rep ^= ((tid>>i)&1) ? P.w[i] : 0u;

    unsigned addr[16];
    float sr[16], si[16];
    #pragma unroll
    for (int z=0;z<16;z++){
      unsigned vm = 0u;
      if (z&1) vm ^= P.v[0];
      if (z&2) vm ^= P.v[1];
      if (z&4) vm ^= P.v[2];
      if (z&8) vm ^= P.v[3];
      addr[z] = rep ^ vm;
      float2 t = s[addr[z]];
      sr[z]=t.x; si[z]=t.y;
    }

    #pragma unroll
    for (int j=0;j<4;j++){
      // role of slot z for gate j = P_j ^ z_j; SU(2) makes the coeff select two sign flips
      const unsigned sgn = (unsigned)(__popc(P.r[j] & rep) & 1) << 31;
      const float4 u = ug_sh[pass*4+j];
      const float ar = u.x;
      const float ai = __uint_as_float(__float_as_uint(u.y) ^ sgn);
      const float br = __uint_as_float(__float_as_uint(u.z) ^ sgn);
      const float bi = u.w;
      #pragma unroll
      for (int z0=0;z0<16;z0++){
        if (z0 & (1<<j)) continue;
        const int z1 = z0 | (1<<j);
        const float xr=sr[z0], xi=si[z0], yr=sr[z1], yi=si[z1];
        // new(z0) = (ar+i*ai)*x + (br+i*bi)*y ; new(z1) = (ar-i*ai)*y + (-br+i*bi)*x
        sr[z0] = ar*xr - ai*xi + br*yr - bi*yi;
        si[z0] = ar*xi + ai*xr + br*yi + bi*yr;
        sr[z1] = ar*yr + ai*yi - br*xr - bi*xi;
        si[z1] = ar*yi - ai*yr + bi*xr - br*xi;
      }
    }

    #pragma unroll
    for (int z=0;z<16;z++) s[addr[z]] = make_float2(sr[z], si[z]);
    __syncthreads();
  }

  // measurement: <Z_q> = sum_p |s[p]|^2 * (1-2*parity(rfin[q]&p)),  p = tid + 256*k
  float pr[16];
  #pragma unroll
  for (int k=0;k<16;k++){ float2 t = s[tid + TPB*k]; pr[k] = t.x*t.x + t.y*t.y; }

  float acc[NQ];
  #pragma unroll
  for (int q=0;q<NQ;q++){
    const unsigned r  = cT.rfin[q];
    const unsigned sl = (unsigned)(__popc(r & (unsigned)tid) & 1) << 31;
    float t = 0.f;
    #pragma unroll
    for (int k=0;k<16;k++){
      unsigned sh = ((unsigned)(__popc((r>>8) & (unsigned)k) & 1) << 31) ^ sl;
      t += __uint_as_float(__float_as_uint(pr[k]) ^ sh);
    }
    acc[q] = t;
  }

  const int lane = tid & 63, wv = tid >> 6;
  #pragma unroll
  for (int q=0;q<NQ;q++){
    float v = acc[q];
    #pragma unroll
    for (int off=32; off>0; off>>=1) v += __shfl_down(v, off, 64);
    if (lane==0) red_sh[wv][q]=v;
  }
  __syncthreads();
  if (tid < NQ) meas_sh[tid] = red_sh[0][tid]+red_sh[1][tid]+red_sh[2][tid]+red_sh[3][tid];
  __syncthreads();

  // epilogue MLP on wave 0: out = tanh(meas@W3+b3)@W4 + b4
  if (tid < 64){
    float a = b3[tid];
    #pragma unroll
    for (int k=0;k<NQ;k++) a = fmaf(meas_sh[k], W3[k*HID+tid], a);
    float h2 = tanhf(a);
    float p0 = h2*W4[tid*2+0];
    float p1 = h2*W4[tid*2+1];
    #pragma unroll
    for (int off=32; off>0; off>>=1){ p0 += __shfl_down(p0,off,64); p1 += __shfl_down(p1,off,64); }
    if (tid==0){ out[bidx*2+0]=p0+b4[0]; out[bidx*2+1]=p1+b4[1]; }
  }
}

extern "C" void kernel_launch(void* const* d_in, const int* in_sizes, int n_in,
                              void* d_out, int out_size, void* d_ws, size_t ws_size,
                              hipStream_t stream)
{
  const float* noise = (const float*)d_in[0];
  const float* W1 = (const float*)d_in[1];
  const float* b1 = (const float*)d_in[2];
  const float* W2 = (const float*)d_in[3];
  const float* b2 = (const float*)d_in[4];
  const float* W3 = (const float*)d_in[5];
  const float* b3 = (const float*)d_in[6];
  const float* W4 = (const float*)d_in[7];
  const float* b4 = (const float*)d_in[8];
  float* out = (float*)d_out;
  const int batch = in_sizes[0] / NQ;   // 4096
  qgen<<<batch, TPB, 0, stream>>>(noise, W1, b1, W2, b2, W3, b3, W4, b4, out);
}

// Round 3
// 266.056 us; speedup vs baseline: 1.2118x; 1.2118x over previous
//
#include <hip/hip_runtime.h>
#include <math.h>

#define NQ   12
#define TPB  256

// ================= compile-time GF(2) machinery =================
// Physical index space x = round-1's storage space (CNOT folding validated on HW):
// pass p gate j pairs x <-> x^v_j^p, role parity(r_j^p & x).
// Per-pass layout L_p: rows 0..3 = r_j (=> role = address bit j, L_p v_j = e_j),
// rows 4..11 = basis of annihilator of span{v}. Storage swizzle e = a ^ f(a),
// f(a) = ((a>>4)&7)<<1 (pair-level xor by t&7) -> conflict-free b128 reads.
// Transition write: e' = g(T_p a), T_p = L_{p+1} L_p^-1, g(x)=x^f(x) (linear ->
// folds into per-bit constants C8 and per-slot constants Tc).

struct GF12 { unsigned row[12]; };

constexpr GF12 gf_id(){ GF12 m{}; for(int i=0;i<12;i++) m.row[i]=1u<<i; return m; }
constexpr GF12 gf_mul(const GF12&A,const GF12&B){
  GF12 r{};
  for(int i=0;i<12;i++){ unsigned acc=0;
    for(int k=0;k<12;k++) if((A.row[i]>>k)&1u) acc ^= B.row[k];
    r.row[i]=acc; }
  return r;
}
constexpr unsigned gf_apply(const GF12&A, unsigned x){
  unsigned y=0;
  for(int i=0;i<12;i++) y |= (unsigned)(__builtin_popcount(A.row[i]&x)&1)<<i;
  return y;
}
constexpr GF12 gf_cnot(int q){ GF12 m=gf_id(); int c=11-q, t=11-((q+1)%12); m.row[t]^=(1u<<c); return m; }
constexpr GF12 gf_inv(const GF12&A){
  unsigned a[12], inv[12];
  for(int i=0;i<12;i++){ a[i]=A.row[i]; inv[i]=1u<<i; }
  for(int c=0;c<12;c++){
    int p=-1;
    for(int r2=c;r2<12;r2++) if((a[r2]>>c)&1u){p=r2;break;}
    if(p<0) continue;                 // singular -> caught by checks
    unsigned ta=a[c]; a[c]=a[p]; a[p]=ta;
    unsigned ti=inv[c]; inv[c]=inv[p]; inv[p]=ti;
    for(int r2=0;r2<12;r2++) if(r2!=c && ((a[r2]>>c)&1u)){ a[r2]^=a[c]; inv[r2]^=inv[c]; }
  }
  GF12 R{}; for(int i=0;i<12;i++) R.row[i]=inv[i];
  return R;
}
constexpr unsigned fmap(unsigned x){ return ((x>>4)&7u)<<1; }
constexpr unsigned gfold(unsigned x){ return x ^ fmap(x); }

struct Tab2 {
  unsigned C8[11][8];    // write-base constants (float2-element index) per t-bit
  unsigned Tc[11][16];   // write per-slot constants (float2-element index)
  unsigned rmeas[12];    // measurement parity rows in final-layout address space
  bool ok;
};

constexpr Tab2 make2(){
  Tab2 T{}; T.ok = true;
  // --- round-1-validated v/r construction ---
  GF12 D = gf_id();
  for (int q=0;q<12;q++) D = gf_mul(gf_cnot(q), D);
  GF12 C = gf_id();
  for (int q=11;q>=0;q--) C = gf_mul(gf_cnot(q), C);
  unsigned V[12][4]{}, R[12][4]{}, rfin[12]{};
  GF12 M = gf_id(), Minv = gf_id();
  for (int l=0;l<4;l++){
    for (int q=0;q<12;q++){
      int b = 11-q;
      unsigned v=0;
      for (int j=0;j<12;j++) v |= ((Minv.row[j]>>b)&1u)<<j;
      V[l*3+q/4][q&3] = v;
      R[l*3+q/4][q&3] = M.row[b];
    }
    M = gf_mul(D,M); Minv = gf_mul(C,Minv);
  }
  for (int q=0;q<12;q++) rfin[q] = M.row[11-q];
  // --- layouts L_p ---
  GF12 L[12]{};
  for (int p=0;p<12;p++){
    for (int j=0;j<4;j++) L[p].row[j] = R[p][j];
    // null space of rows {V[p][*]} via RREF (8 vectors)
    unsigned rr[4] = {V[p][0],V[p][1],V[p][2],V[p][3]};
    int pivcol[4] = {-1,-1,-1,-1};
    int nr=0;
    for (int c2=0;c2<12 && nr<4;c2++){
      int pv=-1;
      for (int i=nr;i<4;i++) if((rr[i]>>c2)&1u){pv=i;break;}
      if (pv<0) continue;
      unsigned tmp=rr[nr]; rr[nr]=rr[pv]; rr[pv]=tmp;
      for (int i=0;i<4;i++) if (i!=nr && ((rr[i]>>c2)&1u)) rr[i]^=rr[nr];
      pivcol[nr]=c2; nr++;
    }
    if (nr!=4) T.ok=false;
    int na=0;
    for (int c2=0;c2<12;c2++){
      bool ispiv=false;
      for (int i=0;i<4;i++) if (pivcol[i]==c2) ispiv=true;
      if (ispiv) continue;
      unsigned x = 1u<<c2;
      for (int i=0;i<4;i++) if ((rr[i]>>c2)&1u) x |= 1u<<pivcol[i];
      if (na<8) L[p].row[4+na] = x;
      na++;
    }
    if (na!=8) T.ok=false;
    for (int j=0;j<4;j++) if (gf_apply(L[p], V[p][j]) != (1u<<j)) T.ok=false;
  }
  // invertibility check for all layouts
  for (int p=0;p<12;p++){
    GF12 I2 = gf_mul(L[p], gf_inv(L[p]));
    for (int i=0;i<12;i++) if (I2.row[i] != (1u<<i)) T.ok=false;
  }
  // --- transitions ---
  for (int p=0;p<11;p++){
    GF12 Tm = gf_mul(L[p+1], gf_inv(L[p]));
    GF12 chk = gf_mul(Tm, L[p]);                 // must equal L[p+1]
    for (int i=0;i<12;i++) if (chk.row[i]!=L[p+1].row[i]) T.ok=false;
    for (int i=0;i<8;i++)  T.C8[p][i] = gfold(gf_apply(Tm, 1u<<(4+i)));
    for (int z=0;z<16;z++) T.Tc[p][z] = gfold(gf_apply(Tm, (unsigned)z));
  }
  // --- measurement rows: rmeas_q = rfin_q . L11^-1 ---
  GF12 Li = gf_inv(L[11]);
  for (int q=0;q<12;q++){
    unsigned rm=0;
    for (int j=0;j<12;j++){
      unsigned colj = gf_apply(Li, 1u<<j);
      rm |= (unsigned)(__builtin_popcount(rfin[q]&colj)&1) << j;
    }
    T.rmeas[q]=rm;
    for (int k2=0;k2<12;k2++){
      unsigned a = gf_apply(L[11], 1u<<k2);
      if ((__builtin_popcount(rm & a)&1) != (__builtin_popcount(rfin[q] & (1u<<k2))&1)) T.ok=false;
    }
  }
  return T;
}

constexpr Tab2 hT2 = make2();
static_assert(hT2.ok, "GF(2) layout table self-check failed");
__constant__ Tab2 cT2 = hT2;

// register slot n_: re/im as static float4 components.
// NOTE: parameter must NOT be named x/y/z/w -> macro would capture the member tokens.
#define SR(n_) (((n_)&1) ? Q[(n_)>>1].z : Q[(n_)>>1].x)
#define SI(n_) (((n_)&1) ? Q[(n_)>>1].w : Q[(n_)>>1].y)

#define GATE(JJ) do { \
    const int _lb = pl + 4*(JJ); \
    const float ar = __uint_as_float((unsigned)__builtin_amdgcn_readlane((int)cur, _lb+0)); \
    const float ai = __uint_as_float((unsigned)__builtin_amdgcn_readlane((int)cur, _lb+1)); \
    const float br = __uint_as_float((unsigned)__builtin_amdgcn_readlane((int)cur, _lb+2)); \
    const float bi = __uint_as_float((unsigned)__builtin_amdgcn_readlane((int)cur, _lb+3)); \
    _Pragma("unroll") \
    for (int s0=0; s0<16; ++s0){ \
      if ((s0 >> (JJ)) & 1) continue; \
      const int s1 = s0 | (1<<(JJ)); \
      const float xr=SR(s0), xi=SI(s0), yr=SR(s1), yi=SI(s1); \
      SR(s0)=fmaf(ar,xr,fmaf(-ai,xi,fmaf(br,yr,-(bi*yi)))); \
      SI(s0)=fmaf(ar,xi,fmaf( ai,xr,fmaf(br,yi,  bi*yr ))); \
      SR(s1)=fmaf(ar,yr,fmaf( ai,yi,fmaf(-br,xr,-(bi*xi)))); \
      SI(s1)=fmaf(ar,yi,fmaf(-ai,yr,fmaf( bi,xr,-(br*xi)))); \
    } \
  } while(0)

__global__ void __launch_bounds__(TPB, 5)
qgen(const float* __restrict__ noise,
     const float* __restrict__ W1, const float* __restrict__ b1,
     const float* __restrict__ W2, const float* __restrict__ b2,
     const float* __restrict__ W3, const float* __restrict__ b3,
     const float* __restrict__ W4, const float* __restrict__ b4,
     float* __restrict__ out)
{
  __shared__ float4 smem[2048];            // exactly 32 KiB -> 5 blocks/CU
  float*  sf = (float*)smem;
  float2* s2 = (float2*)smem;

  const int t = threadIdx.x;
  const int b = blockIdx.x;
  const int lane = t & 63;

  // ---- prologue MLP (scratch aliased into state region) ----
  // ug: floats 0..191 | h: 192..255 | par: 256..399 | noise: 400..411
  if (t < 12) sf[400+t] = noise[b*12+t];
  __syncthreads();
  if (t < 64){
    float a = b1[t];
    #pragma unroll
    for (int k=0;k<12;++k) a = fmaf(sf[400+k], W1[k*64+t], a);
    sf[192+t] = tanhf(a);
  }
  __syncthreads();
  if (t < 144){
    float a = b2[t];
    #pragma unroll 16
    for (int j=0;j<64;++j) a = fmaf(sf[192+j], W2[j*144+t], a);
    sf[256+t] = a;
  }
  __syncthreads();
  if (t < 48){
    float aa = sf[256+3*t+0]*0.5f, bb = sf[256+3*t+1]*0.5f, c = sf[256+3*t+2]*0.5f;
    float sa,ca,sb,cb,sc2,cc;
    __sincosf(aa,&sa,&ca); __sincosf(bb,&sb,&cb); __sincosf(c,&sc2,&cc);
    float A=cb*ca, B=sb*sa, Cc=sb*ca, Dd=cb*sa;
    smem[t] = make_float4(fmaf(cc,A,  sc2*B),  fmaf(cc,B, -sc2*A),
                          fmaf(-cc,Cc,-sc2*Dd), fmaf(sc2,Cc,-cc*Dd));
  }
  __syncthreads();
  // pull all 48 gate float4s (192 floats) into 3 per-lane regs (each wave has a copy)
  const unsigned* su = (const unsigned*)smem;
  const unsigned cu0 = su[lane], cu1 = su[64+lane], cu2 = su[128+lane];
  __syncthreads();

  // ---- init |0..0> (physical address 0 in every layout) ----
  #pragma unroll
  for (int k=0;k<8;++k) smem[t*8+k] = make_float4(0.f,0.f,0.f,0.f);
  if (t==0) s2[0] = make_float2(1.f,0.f);
  __syncthreads();

  // ---- 12 radix-16 passes ----
  const unsigned rq = ((unsigned)t<<3) ^ ((unsigned)t & 7u);  // swizzled float4 read base
  float4 Q[8];

  #pragma unroll 1
  for (int p=0; p<12; ++p){
    #pragma unroll
    for (int k=0;k<8;++k) Q[k] = smem[rq ^ (unsigned)k];      // conflict-free b128

    const int ps = p>>2;
    unsigned cur = (ps==0) ? cu0 : ((ps==1) ? cu1 : cu2);
    const int pl = (p&3)<<4;
    GATE(0); GATE(1); GATE(2); GATE(3);

    if (p==11) break;                                          // last pass stays in regs
    __syncthreads();                                           // all reads done
    unsigned wb = 0;
    #pragma unroll
    for (int i=0;i<8;++i) wb ^= (((unsigned)t>>i)&1u) ? cT2.C8[p][i] : 0u;
    #pragma unroll
    for (int z=0; z<16; ++z)
      s2[wb ^ cT2.Tc[p][z]] = make_float2(SR(z), SI(z));       // scatter to next layout
    __syncthreads();                                           // all writes done
  }

  __syncthreads();   // everyone finished reading state -> LDS reusable as scratch

  // ---- measurement directly from registers ----
  float pr[16];
  #pragma unroll
  for (int z=0; z<16; ++z) pr[z] = fmaf(SR(z),SR(z), SI(z)*SI(z));
  float acc[12];
  #pragma unroll
  for (int q=0;q<12;++q){
    const unsigned rm = hT2.rmeas[q];
    const unsigned sb = ((unsigned)(__popc((rm>>4)&(unsigned)t)&1))<<31;
    float a = 0.f;
    #pragma unroll
    for (int z=0;z<16;++z){
      const unsigned sc = ((unsigned)(__builtin_popcount(rm & (unsigned)z)&1))<<31; // folds
      a += __uint_as_float(__float_as_uint(pr[z]) ^ sb ^ sc);
    }
    acc[q]=a;
  }

  const int wv = t >> 6;
  #pragma unroll
  for (int q=0;q<12;++q){
    float v = acc[q];
    #pragma unroll
    for (int off=32; off>0; off>>=1) v += __shfl_down(v, off, 64);
    if (lane==0) sf[wv*12+q] = v;
  }
  __syncthreads();
  if (t < 12) sf[64+t] = sf[t] + sf[12+t] + sf[24+t] + sf[36+t];
  __syncthreads();

  // ---- epilogue MLP on wave 0 ----
  if (t < 64){
    float a = b3[t];
    #pragma unroll
    for (int k=0;k<12;++k) a = fmaf(sf[64+k], W3[k*64+t], a);
    float h2 = tanhf(a);
    float p0 = h2*W4[2*t+0], p1 = h2*W4[2*t+1];
    #pragma unroll
    for (int off=32; off>0; off>>=1){ p0 += __shfl_down(p0,off,64); p1 += __shfl_down(p1,off,64); }
    if (t==0){ out[2*b+0]=p0+b4[0]; out[2*b+1]=p1+b4[1]; }
  }
}

extern "C" void kernel_launch(void* const* d_in, const int* in_sizes, int n_in,
                              void* d_out, int out_size, void* d_ws, size_t ws_size,
                              hipStream_t stream)
{
  const float* noise = (const float*)d_in[0];
  const float* W1 = (const float*)d_in[1];
  const float* b1 = (const float*)d_in[2];
  const float* W2 = (const float*)d_in[3];
  const float* b2 = (const float*)d_in[4];
  const float* W3 = (const float*)d_in[5];
  const float* b3 = (const float*)d_in[6];
  const float* W4 = (const float*)d_in[7];
  const float* b4 = (const float*)d_in[8];
  float* out = (float*)d_out;
  const int batch = in_sizes[0] / NQ;   // 4096
  qgen<<<batch, TPB, 0, stream>>>(noise, W1, b1, W2, b2, W3, b3, W4, b4, out);
}